// Round 6
// baseline (365.741 us; speedup 1.0000x reference)
//
#include <hip/hip_runtime.h>
#include <hip/hip_bf16.h>
#include <math.h>
#include <stdint.h>

#define B_     16
#define CI_    512
#define CO_    512
#define HH     64
#define WW     64
#define STYLE_ 512

typedef __bf16 bf16x8 __attribute__((ext_vector_type(8)));
typedef float f32x4 __attribute__((ext_vector_type(4)));

// ---- workspace layout (bytes) ----
#define WS_S     0                    // s[b][ci] f32, 32 KB
#define WS_DEMOD 32768                // demod[b][co] f32, 32 KB
#define WS_WSQ   65536                // wsq[ci][co] f32, 1 MB
#define WS_WB    1114112              // wb[ci/32][t][co][32] bf16, 4.7 MB
#define WS_XS    5832704              // xs[ci/32][b][66][x][32] bf16 (guard rows), 69.2 MB

__device__ __forceinline__ void gload16(const void* g, void* l) {
    __builtin_amdgcn_global_load_lds((const __attribute__((address_space(1))) uint32_t*)g,
                                     (__attribute__((address_space(3))) uint32_t*)l, 16, 0, 0);
}

// ---------- s[b][ci] = style[b] . mod_w[ci] / sqrt(512) + mod_b[ci]
__global__ void k_style(const float* __restrict__ style, const float* __restrict__ mod_w,
                        const float* __restrict__ mod_b, float* __restrict__ s_out) {
    int b  = blockIdx.x;
    int ci = threadIdx.x;
    const float scale = 0.044194173824159216f; // 1/sqrt(512)
    float acc = 0.f;
    const float* st = style + b * STYLE_;
    const float* mw = mod_w + (size_t)ci * STYLE_;
    for (int j = 0; j < STYLE_; ++j) acc += st[j] * mw[j];
    s_out[b * CI_ + ci] = acc * scale + mod_b[ci];
}

// ---------- wsq[ci][co] = sum_tap w^2  AND  wb[ci>>5][t][co][ci&31] = bf16(w)
__global__ __launch_bounds__(256) void k_wprep(const float* __restrict__ weight,
                                               float* __restrict__ wsq, __bf16* __restrict__ wb) {
    int p = blockIdx.x * 256 + threadIdx.x;   // co*512 + ci
    int co = p >> 9, ci = p & 511;
    const float* wp = weight + (size_t)p * 9;
    float acc = 0.f;
    #pragma unroll
    for (int t = 0; t < 9; ++t) {
        float v = wp[t];
        acc += v * v;
        wb[((((size_t)(ci >> 5) * 9 + t) * CO_) + co) * 32 + (ci & 31)] = (__bf16)v;
    }
    wsq[(size_t)ci * CO_ + co] = acc;
}

// ---------- demod[b][co] = rsqrt(w_scale^2 * sum_ci s^2 * wsq + 1e-8)
__global__ void k_demod(const float* __restrict__ s, const float* __restrict__ wsq,
                        float* __restrict__ demod) {
    int b = blockIdx.x, co = threadIdx.x;
    const float w_scale2 = 1.0f / 4608.0f;
    float acc = 0.f;
    const float* sb = s + b * CI_;
    for (int ci = 0; ci < CI_; ++ci) { float sv = sb[ci]; acc += sv * sv * wsq[(size_t)ci * CO_ + co]; }
    demod[b * CO_ + co] = 1.0f / sqrtf(acc * w_scale2 + 1e-8f);
}

// ---------- xs[ci>>5][b][y+1][x][ci&31] = bf16(x[b][ci][y][x]*s*w_scale); y==0/63 also zero guards
__global__ __launch_bounds__(256) void k_xs(const float* __restrict__ x, const float* __restrict__ s,
                                            __bf16* __restrict__ xs) {
    __shared__ float Lt[64][65];
    const int y = blockIdx.x, b = blockIdx.y;
    const int tid = threadIdx.x;
    const float w_scale = 0.014731391274719739f; // 1/sqrt(512*9)
    for (int ci0 = 0; ci0 < CI_; ci0 += 64) {
        for (int i = tid; i < 64 * 16; i += 256) {     // float4 loads
            int ci = i >> 4, x4 = (i & 15) * 4;
            const float4 v = *(const float4*)&x[((size_t)(b * CI_ + ci0 + ci) * HH + y) * WW + x4];
            float sc = s[b * CI_ + ci0 + ci] * w_scale;
            Lt[ci][x4]     = v.x * sc;
            Lt[ci][x4 + 1] = v.y * sc;
            Lt[ci][x4 + 2] = v.z * sc;
            Lt[ci][x4 + 3] = v.w * sc;
        }
        __syncthreads();
        for (int o = tid; o < 512; o += 256) {
            int xx = o >> 3, oct = o & 7;
            int cb = ci0 + oct * 8;
            bf16x8 v;
            #pragma unroll
            for (int j = 0; j < 8; ++j) v[j] = (__bf16)Lt[oct * 8 + j][xx];
            size_t idx = ((((size_t)(cb >> 5) * 16 + b) * 66 + (y + 1)) * 64 + xx) * 32 + (cb & 31);
            *(bf16x8*)&xs[idx] = v;
        }
        __syncthreads();
    }
    // guard rows (y = -1 and y = 64)
    if (y == 0 || y == 63) {
        const int row = (y == 0) ? 0 : 65;
        uint32_t* xs32 = (uint32_t*)xs;
        for (int c = 0; c < 16; ++c)
            for (int i = tid; i < 1024; i += 256)
                xs32[(((size_t)c * 16 + b) * 66 + row) * 1024 + i] = 0;
    }
}

// ---------- conv: bf16 implicit GEMM, dbuf + counted vmcnt + A-hoist + setprio
// 1024 blocks, XCD remap; 512 thr / 8 waves; wave w: 64co x 1y x 64x; acc 4x4
#define XB 42240   // 10 rowblk * 66 * 64 B
#define WB 36864   // 9 * 64 * 64 B

__global__ __launch_bounds__(512, 2) void k_conv(
    const __bf16* __restrict__ xs, const __bf16* __restrict__ wb,
    const float* __restrict__ demod, float* __restrict__ out)
{
    __shared__ __align__(128) char smem[2 * XB + 2 * WB];

    const int tid  = threadIdx.x;
    const int lane = tid & 63;
    const int wave = tid >> 6;

    const int bid  = blockIdx.x;
    const int r8   = bid & 7;            // XCD
    const int q    = bid >> 3;
    const int co0  = (q & 7) * 64;
    const int pair = (q >> 3) | (r8 << 4);
    const int y0   = (pair & 7) * 8;
    const int b    = pair >> 3;

    const int m  = lane & 15;
    const int g  = lane >> 4;
    const int qA = g ^ ((m >> 1) & 3);

    // zero x-halo rows (xr=0,65) of all 10 rowblocks in BOTH X buffers
    for (int i = tid; i < 640; i += 512) {
        int dw = i & 15, h = i >> 4;
        int buf = h / 20, hh = h % 20;
        int rr = hh >> 1, side = hh & 1;
        ((uint32_t*)smem)[buf * (XB / 4) + (rr * 66 + side * 65) * 16 + dw] = 0;
    }
    asm volatile("s_waitcnt lgkmcnt(0)" ::: "memory");

    // ---- precomputed staging offsets (per thread, chunk-invariant)
    uint32_t soff[10];                 // global element offsets
    uint32_t sdst[10];                 // LDS byte offsets (within selected buffer scheme)
    const __bf16* sb;
    size_t sstride;
    uint32_t selstride;
    if (wave < 4) {
        sb = xs + (size_t)b * (66 * 64 * 32);
        sstride = (size_t)16 * 66 * 64 * 32;
        selstride = XB;
        #pragma unroll
        for (int i = 0; i < 10; ++i) {
            int o = wave * 10 + i, r = o >> 2, seg = o & 3;
            int p = seg * 64 + lane;
            int xr = 1 + (p >> 2), qd = p & 3;
            int rowg = r * 66 + xr;
            int sq = qd ^ ((rowg >> 1) & 3);
            soff[i] = (uint32_t)(((y0 + r) * 64 + (xr - 1)) * 32 + sq * 8);
            sdst[i] = (uint32_t)((r * 66 + 1) * 64 + seg * 1024);
        }
    } else {
        sb = wb;
        sstride = (size_t)9 * CO_ * 32;
        selstride = WB;
        #pragma unroll
        for (int i = 0; i < 9; ++i) {
            int j = (wave - 4) * 9 + i;
            int p = j * 64 + lane;
            int row = p >> 2, qd = p & 3;
            int sq = qd ^ ((row >> 1) & 3);
            soff[i] = (uint32_t)(((row >> 6) * CO_ + co0 + (row & 63)) * 32 + sq * 8);
            sdst[i] = (uint32_t)(2 * XB + j * 1024);
        }
        soff[9] = 0; sdst[9] = 2 * XB;   // unused
    }

    // ---- precomputed B-read byte bases (per kh,kw; nt adds 1024)
    uint32_t bbase[9];
    #pragma unroll
    for (int kh = 0; kh < 3; ++kh)
        #pragma unroll
        for (int kw = 0; kw < 3; ++kw) {
            int R = (wave + kh) * 66 + m + kw;
            int qB = g ^ ((R >> 1) & 3);
            bbase[kh * 3 + kw] = (uint32_t)(R * 64 + qB * 16);
        }
    const uint32_t abase = (uint32_t)(m * 64 + qA * 16);

    f32x4 acc[4][4];
    #pragma unroll
    for (int mi = 0; mi < 4; ++mi)
        #pragma unroll
        for (int nt = 0; nt < 4; ++nt) acc[mi][nt] = (f32x4){0.f, 0.f, 0.f, 0.f};

    auto stage = [&](const __bf16* base, int sel) {
        uint32_t so = sel * selstride;
        if (wave < 4) {
            #pragma unroll
            for (int i = 0; i < 10; ++i) gload16(base + soff[i], smem + so + sdst[i]);
        } else {
            #pragma unroll
            for (int i = 0; i < 9; ++i) gload16(base + soff[i], smem + so + sdst[i]);
        }
    };

    stage(sb, 0);

    for (int t = 0; t < 16; ++t) {
        if (t < 15) {
            sb += sstride;
            stage(sb, (t + 1) & 1);
            if (wave < 4) asm volatile("s_waitcnt vmcnt(10)" ::: "memory");
            else          asm volatile("s_waitcnt vmcnt(9)"  ::: "memory");
        } else {
            asm volatile("s_waitcnt vmcnt(0)" ::: "memory");
        }
        __builtin_amdgcn_s_barrier();

        const char* xbuf = smem + (t & 1) * XB;
        const char* wbuf = smem + 2 * XB + (t & 1) * WB + abase;

        // hoist all 36 A-fragments to registers
        bf16x8 af[9][4];
        #pragma unroll
        for (int tp = 0; tp < 9; ++tp)
            #pragma unroll
            for (int mi = 0; mi < 4; ++mi)
                af[tp][mi] = *(const bf16x8*)(wbuf + tp * 4096 + mi * 1024);

        __builtin_amdgcn_s_setprio(1);
        #pragma unroll
        for (int tp = 0; tp < 9; ++tp) {
            #pragma unroll
            for (int nt = 0; nt < 4; ++nt) {
                bf16x8 bv = *(const bf16x8*)(xbuf + bbase[tp] + nt * 1024);
                acc[0][nt] = __builtin_amdgcn_mfma_f32_16x16x32_bf16(af[tp][0], bv, acc[0][nt], 0, 0, 0);
                acc[1][nt] = __builtin_amdgcn_mfma_f32_16x16x32_bf16(af[tp][1], bv, acc[1][nt], 0, 0, 0);
                acc[2][nt] = __builtin_amdgcn_mfma_f32_16x16x32_bf16(af[tp][2], bv, acc[2][nt], 0, 0, 0);
                acc[3][nt] = __builtin_amdgcn_mfma_f32_16x16x32_bf16(af[tp][3], bv, acc[3][nt], 0, 0, 0);
            }
        }
        __builtin_amdgcn_s_setprio(0);
        __builtin_amdgcn_s_barrier();
    }

    // ---- epilogue: out[b][co][y][x] = acc * demod[b][co]
    const int y = y0 + wave;
    #pragma unroll
    for (int mi = 0; mi < 4; ++mi) {
        #pragma unroll
        for (int j = 0; j < 4; ++j) {
            const int co = co0 + mi * 16 + g * 4 + j;
            const float dm = demod[b * CO_ + co];
            float* op = out + ((size_t)(b * CO_ + co) * HH + y) * WW;
            #pragma unroll
            for (int nt = 0; nt < 4; ++nt)
                op[nt * 16 + m] = acc[mi][nt][j] * dm;
        }
    }
}

extern "C" void kernel_launch(void* const* d_in, const int* in_sizes, int n_in,
                              void* d_out, int out_size, void* d_ws, size_t ws_size,
                              hipStream_t stream) {
    const float* x      = (const float*)d_in[0];
    const float* style  = (const float*)d_in[1];
    const float* weight = (const float*)d_in[2];
    const float* mod_w  = (const float*)d_in[3];
    const float* mod_b  = (const float*)d_in[4];
    float* out = (float*)d_out;

    char* wsb = (char*)d_ws;
    float*  s_buf = (float*)(wsb + WS_S);
    float*  demod = (float*)(wsb + WS_DEMOD);
    float*  wsq   = (float*)(wsb + WS_WSQ);
    __bf16* wb    = (__bf16*)(wsb + WS_WB);
    __bf16* xs    = (__bf16*)(wsb + WS_XS);

    k_style<<<dim3(B_), dim3(CI_), 0, stream>>>(style, mod_w, mod_b, s_buf);
    k_wprep<<<dim3(CO_ * CI_ / 256), dim3(256), 0, stream>>>(weight, wsq, wb);
    k_demod<<<dim3(B_), dim3(CO_), 0, stream>>>(s_buf, wsq, demod);
    k_xs<<<dim3(HH, B_), dim3(256), 0, stream>>>(x, s_buf, xs);
    k_conv<<<dim3(1024), dim3(512), 0, stream>>>(xs, wb, demod, out);
}

// Round 7
// 340.989 us; speedup vs baseline: 1.0726x; 1.0726x over previous
//
#include <hip/hip_runtime.h>
#include <hip/hip_bf16.h>
#include <math.h>
#include <stdint.h>

#define B_     16
#define CI_    512
#define CO_    512
#define HH     64
#define WW     64
#define STYLE_ 512

typedef __bf16 bf16x8 __attribute__((ext_vector_type(8)));
typedef float f32x4 __attribute__((ext_vector_type(4)));

// ---- workspace layout (bytes) ----
#define WS_S     0                    // s[b][ci] f32, 32 KB
#define WS_DEMOD 32768                // demod[b][co] f32, 32 KB
#define WS_WSQ   65536                // wsq[ci][co] f32, 1 MB
#define WS_WB    1114112              // wb[ci/32][t][co][32] bf16, 4.7 MB
#define WS_XS    5832704              // xs[ci/32][b][66][x][32] bf16 (guard rows), 69.2 MB

__device__ __forceinline__ void gload16(const void* g, void* l) {
    __builtin_amdgcn_global_load_lds((const __attribute__((address_space(1))) uint32_t*)g,
                                     (__attribute__((address_space(3))) uint32_t*)l, 16, 0, 0);
}

// ---------- s[b][ci] = style[b] . mod_w[ci] / sqrt(512) + mod_b[ci]
__global__ void k_style(const float* __restrict__ style, const float* __restrict__ mod_w,
                        const float* __restrict__ mod_b, float* __restrict__ s_out) {
    int b  = blockIdx.x;
    int ci = threadIdx.x;
    const float scale = 0.044194173824159216f; // 1/sqrt(512)
    float acc = 0.f;
    const float* st = style + b * STYLE_;
    const float* mw = mod_w + (size_t)ci * STYLE_;
    for (int j = 0; j < STYLE_; ++j) acc += st[j] * mw[j];
    s_out[b * CI_ + ci] = acc * scale + mod_b[ci];
}

// ---------- wsq[ci][co] = sum_tap w^2  AND  wb[ci>>5][t][co][ci&31] = bf16(w)
__global__ __launch_bounds__(256) void k_wprep(const float* __restrict__ weight,
                                               float* __restrict__ wsq, __bf16* __restrict__ wb) {
    int p = blockIdx.x * 256 + threadIdx.x;   // co*512 + ci
    int co = p >> 9, ci = p & 511;
    const float* wp = weight + (size_t)p * 9;
    float acc = 0.f;
    #pragma unroll
    for (int t = 0; t < 9; ++t) {
        float v = wp[t];
        acc += v * v;
        wb[((((size_t)(ci >> 5) * 9 + t) * CO_) + co) * 32 + (ci & 31)] = (__bf16)v;
    }
    wsq[(size_t)ci * CO_ + co] = acc;
}

// ---------- demod[b][co] = rsqrt(w_scale^2 * sum_ci s^2 * wsq + 1e-8)
__global__ void k_demod(const float* __restrict__ s, const float* __restrict__ wsq,
                        float* __restrict__ demod) {
    int b = blockIdx.x, co = threadIdx.x;
    const float w_scale2 = 1.0f / 4608.0f;
    float acc = 0.f;
    const float* sb = s + b * CI_;
    for (int ci = 0; ci < CI_; ++ci) { float sv = sb[ci]; acc += sv * sv * wsq[(size_t)ci * CO_ + co]; }
    demod[b * CO_ + co] = 1.0f / sqrtf(acc * w_scale2 + 1e-8f);
}

// ---------- xs[ci>>5][b][y+1][x][ci&31] = bf16(x[b][ci][y][x]*s*w_scale); y==0/63 also zero guards
__global__ __launch_bounds__(256) void k_xs(const float* __restrict__ x, const float* __restrict__ s,
                                            __bf16* __restrict__ xs) {
    __shared__ float Lt[64][65];
    const int y = blockIdx.x, b = blockIdx.y;
    const int tid = threadIdx.x;
    const float w_scale = 0.014731391274719739f; // 1/sqrt(512*9)
    for (int ci0 = 0; ci0 < CI_; ci0 += 64) {
        for (int i = tid; i < 64 * 16; i += 256) {     // float4 loads
            int ci = i >> 4, x4 = (i & 15) * 4;
            const float4 v = *(const float4*)&x[((size_t)(b * CI_ + ci0 + ci) * HH + y) * WW + x4];
            float sc = s[b * CI_ + ci0 + ci] * w_scale;
            Lt[ci][x4]     = v.x * sc;
            Lt[ci][x4 + 1] = v.y * sc;
            Lt[ci][x4 + 2] = v.z * sc;
            Lt[ci][x4 + 3] = v.w * sc;
        }
        __syncthreads();
        for (int o = tid; o < 512; o += 256) {
            int xx = o >> 3, oct = o & 7;
            int cb = ci0 + oct * 8;
            bf16x8 v;
            #pragma unroll
            for (int j = 0; j < 8; ++j) v[j] = (__bf16)Lt[oct * 8 + j][xx];
            size_t idx = ((((size_t)(cb >> 5) * 16 + b) * 66 + (y + 1)) * 64 + xx) * 32 + (cb & 31);
            *(bf16x8*)&xs[idx] = v;
        }
        __syncthreads();
    }
    // guard rows (y = -1 and y = 64)
    if (y == 0 || y == 63) {
        const int row = (y == 0) ? 0 : 65;
        uint32_t* xs32 = (uint32_t*)xs;
        for (int c = 0; c < 16; ++c)
            for (int i = tid; i < 1024; i += 256)
                xs32[(((size_t)c * 16 + b) * 66 + row) * 1024 + i] = 0;
    }
}

// ---------- conv: bf16 implicit GEMM, dbuf + counted vmcnt + addr-precompute + setprio
// 1024 blocks, XCD remap; 512 thr / 8 waves; wave w: 64co x 1y x 64x; acc 4x4
// round-5 compute schedule (per-tap A-reads, compiler-pipelined); NO full A-hoist, NO VGPR cap
#define XB 42240   // 10 rowblk * 66 * 64 B
#define WB 36864   // 9 * 64 * 64 B

__global__ __launch_bounds__(512, 1) void k_conv(
    const __bf16* __restrict__ xs, const __bf16* __restrict__ wb,
    const float* __restrict__ demod, float* __restrict__ out)
{
    __shared__ __align__(128) char smem[2 * XB + 2 * WB];

    const int tid  = threadIdx.x;
    const int lane = tid & 63;
    const int wave = tid >> 6;

    const int bid  = blockIdx.x;
    const int r8   = bid & 7;            // XCD
    const int q    = bid >> 3;
    const int co0  = (q & 7) * 64;
    const int pair = (q >> 3) | (r8 << 4);
    const int y0   = (pair & 7) * 8;
    const int b    = pair >> 3;

    const int m  = lane & 15;
    const int g  = lane >> 4;
    const int qA = g ^ ((m >> 1) & 3);

    // zero x-halo rows (xr=0,65) of all 10 rowblocks in BOTH X buffers
    for (int i = tid; i < 640; i += 512) {
        int dw = i & 15, h = i >> 4;
        int buf = h / 20, hh = h % 20;
        int rr = hh >> 1, side = hh & 1;
        ((uint32_t*)smem)[buf * (XB / 4) + (rr * 66 + side * 65) * 16 + dw] = 0;
    }
    asm volatile("s_waitcnt lgkmcnt(0)" ::: "memory");

    // ---- precomputed staging offsets (per thread, chunk-invariant)
    uint32_t soff[10];                 // global element offsets
    uint32_t sdst[10];                 // LDS byte offsets
    const __bf16* sb;
    size_t sstride;
    uint32_t selstride;
    if (wave < 4) {
        sb = xs + (size_t)b * (66 * 64 * 32);
        sstride = (size_t)16 * 66 * 64 * 32;
        selstride = XB;
        #pragma unroll
        for (int i = 0; i < 10; ++i) {
            int o = wave * 10 + i, r = o >> 2, seg = o & 3;
            int p = seg * 64 + lane;
            int xr = 1 + (p >> 2), qd = p & 3;
            int rowg = r * 66 + xr;
            int sq = qd ^ ((rowg >> 1) & 3);
            soff[i] = (uint32_t)(((y0 + r) * 64 + (xr - 1)) * 32 + sq * 8);
            sdst[i] = (uint32_t)((r * 66 + 1) * 64 + seg * 1024);
        }
    } else {
        sb = wb;
        sstride = (size_t)9 * CO_ * 32;
        selstride = WB;
        #pragma unroll
        for (int i = 0; i < 9; ++i) {
            int j = (wave - 4) * 9 + i;
            int p = j * 64 + lane;
            int row = p >> 2, qd = p & 3;
            int sq = qd ^ ((row >> 1) & 3);
            soff[i] = (uint32_t)(((row >> 6) * CO_ + co0 + (row & 63)) * 32 + sq * 8);
            sdst[i] = (uint32_t)(2 * XB + j * 1024);
        }
        soff[9] = 0; sdst[9] = 2 * XB;   // unused
    }

    // ---- precomputed B-read byte bases (per kh,kw; nt adds 1024; nt doesn't affect quad swizzle)
    uint32_t bbase[9];
    #pragma unroll
    for (int kh = 0; kh < 3; ++kh)
        #pragma unroll
        for (int kw = 0; kw < 3; ++kw) {
            int R = (wave + kh) * 66 + m + kw;
            int qB = g ^ ((R >> 1) & 3);
            bbase[kh * 3 + kw] = (uint32_t)(R * 64 + qB * 16);
        }
    const uint32_t abase = (uint32_t)(m * 64 + qA * 16);

    f32x4 acc[4][4];
    #pragma unroll
    for (int mi = 0; mi < 4; ++mi)
        #pragma unroll
        for (int nt = 0; nt < 4; ++nt) acc[mi][nt] = (f32x4){0.f, 0.f, 0.f, 0.f};

    auto stage = [&](const __bf16* base, int sel) {
        uint32_t so = sel * selstride;
        if (wave < 4) {
            #pragma unroll
            for (int i = 0; i < 10; ++i) gload16(base + soff[i], smem + so + sdst[i]);
        } else {
            #pragma unroll
            for (int i = 0; i < 9; ++i) gload16(base + soff[i], smem + so + sdst[i]);
        }
    };

    stage(sb, 0);

    for (int t = 0; t < 16; ++t) {
        if (t < 15) {
            sb += sstride;
            stage(sb, (t + 1) & 1);
            if (wave < 4) asm volatile("s_waitcnt vmcnt(10)" ::: "memory");
            else          asm volatile("s_waitcnt vmcnt(9)"  ::: "memory");
        } else {
            asm volatile("s_waitcnt vmcnt(0)" ::: "memory");
        }
        __builtin_amdgcn_s_barrier();

        const char* xbuf = smem + (t & 1) * XB;
        const char* wbuf = smem + 2 * XB + (t & 1) * WB + abase;

        __builtin_amdgcn_s_setprio(1);
        #pragma unroll
        for (int tp = 0; tp < 9; ++tp) {
            bf16x8 a0 = *(const bf16x8*)(wbuf + tp * 4096);
            bf16x8 a1 = *(const bf16x8*)(wbuf + tp * 4096 + 1024);
            bf16x8 a2 = *(const bf16x8*)(wbuf + tp * 4096 + 2048);
            bf16x8 a3 = *(const bf16x8*)(wbuf + tp * 4096 + 3072);
            #pragma unroll
            for (int nt = 0; nt < 4; ++nt) {
                bf16x8 bv = *(const bf16x8*)(xbuf + bbase[tp] + nt * 1024);
                acc[0][nt] = __builtin_amdgcn_mfma_f32_16x16x32_bf16(a0, bv, acc[0][nt], 0, 0, 0);
                acc[1][nt] = __builtin_amdgcn_mfma_f32_16x16x32_bf16(a1, bv, acc[1][nt], 0, 0, 0);
                acc[2][nt] = __builtin_amdgcn_mfma_f32_16x16x32_bf16(a2, bv, acc[2][nt], 0, 0, 0);
                acc[3][nt] = __builtin_amdgcn_mfma_f32_16x16x32_bf16(a3, bv, acc[3][nt], 0, 0, 0);
            }
        }
        __builtin_amdgcn_s_setprio(0);
        __builtin_amdgcn_s_barrier();
    }

    // ---- epilogue: out[b][co][y][x] = acc * demod[b][co]
    const int y = y0 + wave;
    #pragma unroll
    for (int mi = 0; mi < 4; ++mi) {
        #pragma unroll
        for (int j = 0; j < 4; ++j) {
            const int co = co0 + mi * 16 + g * 4 + j;
            const float dm = demod[b * CO_ + co];
            float* op = out + ((size_t)(b * CO_ + co) * HH + y) * WW;
            #pragma unroll
            for (int nt = 0; nt < 4; ++nt)
                op[nt * 16 + m] = acc[mi][nt][j] * dm;
        }
    }
}

extern "C" void kernel_launch(void* const* d_in, const int* in_sizes, int n_in,
                              void* d_out, int out_size, void* d_ws, size_t ws_size,
                              hipStream_t stream) {
    const float* x      = (const float*)d_in[0];
    const float* style  = (const float*)d_in[1];
    const float* weight = (const float*)d_in[2];
    const float* mod_w  = (const float*)d_in[3];
    const float* mod_b  = (const float*)d_in[4];
    float* out = (float*)d_out;

    char* wsb = (char*)d_ws;
    float*  s_buf = (float*)(wsb + WS_S);
    float*  demod = (float*)(wsb + WS_DEMOD);
    float*  wsq   = (float*)(wsb + WS_WSQ);
    __bf16* wb    = (__bf16*)(wsb + WS_WB);
    __bf16* xs    = (__bf16*)(wsb + WS_XS);

    k_style<<<dim3(B_), dim3(CI_), 0, stream>>>(style, mod_w, mod_b, s_buf);
    k_wprep<<<dim3(CO_ * CI_ / 256), dim3(256), 0, stream>>>(weight, wsq, wb);
    k_demod<<<dim3(B_), dim3(CO_), 0, stream>>>(s_buf, wsq, demod);
    k_xs<<<dim3(HH, B_), dim3(256), 0, stream>>>(x, s_buf, xs);
    k_conv<<<dim3(1024), dim3(512), 0, stream>>>(xs, wb, demod, out);
}

// Round 8
// 337.444 us; speedup vs baseline: 1.0839x; 1.0105x over previous
//
#include <hip/hip_runtime.h>
#include <hip/hip_bf16.h>
#include <math.h>
#include <stdint.h>

#define B_     16
#define CI_    512
#define CO_    512
#define HH     64
#define WW     64
#define STYLE_ 512

typedef __bf16 bf16x8 __attribute__((ext_vector_type(8)));
typedef float f32x4 __attribute__((ext_vector_type(4)));

// ---- workspace layout (bytes) ----
#define WS_S     0                    // s[b][ci] f32, 32 KB
#define WS_DEMOD 32768                // demod[b][co] f32, 32 KB
#define WS_WSQ   65536                // wsq[ci][co] f32, 1 MB
#define WS_WB    1114112              // wb[ci/32][t][co][32] bf16, 4.7 MB
#define WS_XS    5832704              // xs[ci/32][b][66][x][32] bf16 (guard rows), 69.2 MB

__device__ __forceinline__ void gload16(const void* g, void* l) {
    __builtin_amdgcn_global_load_lds((const __attribute__((address_space(1))) uint32_t*)g,
                                     (__attribute__((address_space(3))) uint32_t*)l, 16, 0, 0);
}

// ---------- s[b][ci] = style[b] . mod_w[ci] / sqrt(512) + mod_b[ci]
__global__ void k_style(const float* __restrict__ style, const float* __restrict__ mod_w,
                        const float* __restrict__ mod_b, float* __restrict__ s_out) {
    int b  = blockIdx.x;
    int ci = threadIdx.x;
    const float scale = 0.044194173824159216f; // 1/sqrt(512)
    float acc = 0.f;
    const float* st = style + b * STYLE_;
    const float* mw = mod_w + (size_t)ci * STYLE_;
    for (int j = 0; j < STYLE_; ++j) acc += st[j] * mw[j];
    s_out[b * CI_ + ci] = acc * scale + mod_b[ci];
}

// ---------- wsq[ci][co] = sum_tap w^2  AND  wb[ci>>5][t][co][ci&31] = bf16(w)
__global__ __launch_bounds__(256) void k_wprep(const float* __restrict__ weight,
                                               float* __restrict__ wsq, __bf16* __restrict__ wb) {
    int p = blockIdx.x * 256 + threadIdx.x;   // co*512 + ci
    int co = p >> 9, ci = p & 511;
    const float* wp = weight + (size_t)p * 9;
    float acc = 0.f;
    #pragma unroll
    for (int t = 0; t < 9; ++t) {
        float v = wp[t];
        acc += v * v;
        wb[((((size_t)(ci >> 5) * 9 + t) * CO_) + co) * 32 + (ci & 31)] = (__bf16)v;
    }
    wsq[(size_t)ci * CO_ + co] = acc;
}

// ---------- demod[b][co] = rsqrt(w_scale^2 * sum_ci s^2 * wsq + 1e-8)
__global__ void k_demod(const float* __restrict__ s, const float* __restrict__ wsq,
                        float* __restrict__ demod) {
    int b = blockIdx.x, co = threadIdx.x;
    const float w_scale2 = 1.0f / 4608.0f;
    float acc = 0.f;
    const float* sb = s + b * CI_;
    for (int ci = 0; ci < CI_; ++ci) { float sv = sb[ci]; acc += sv * sv * wsq[(size_t)ci * CO_ + co]; }
    demod[b * CO_ + co] = 1.0f / sqrtf(acc * w_scale2 + 1e-8f);
}

// ---------- xs[ci>>5][b][y+1][x][ci&31] = bf16(x[b][ci][y][x]*s*w_scale); y==0/63 also zero guards
__global__ __launch_bounds__(256) void k_xs(const float* __restrict__ x, const float* __restrict__ s,
                                            __bf16* __restrict__ xs) {
    __shared__ float Lt[64][65];
    const int y = blockIdx.x, b = blockIdx.y;
    const int tid = threadIdx.x;
    const float w_scale = 0.014731391274719739f; // 1/sqrt(512*9)
    for (int ci0 = 0; ci0 < CI_; ci0 += 64) {
        for (int i = tid; i < 64 * 16; i += 256) {     // float4 loads
            int ci = i >> 4, x4 = (i & 15) * 4;
            const float4 v = *(const float4*)&x[((size_t)(b * CI_ + ci0 + ci) * HH + y) * WW + x4];
            float sc = s[b * CI_ + ci0 + ci] * w_scale;
            Lt[ci][x4]     = v.x * sc;
            Lt[ci][x4 + 1] = v.y * sc;
            Lt[ci][x4 + 2] = v.z * sc;
            Lt[ci][x4 + 3] = v.w * sc;
        }
        __syncthreads();
        for (int o = tid; o < 512; o += 256) {
            int xx = o >> 3, oct = o & 7;
            int cb = ci0 + oct * 8;
            bf16x8 v;
            #pragma unroll
            for (int j = 0; j < 8; ++j) v[j] = (__bf16)Lt[oct * 8 + j][xx];
            size_t idx = ((((size_t)(cb >> 5) * 16 + b) * 66 + (y + 1)) * 64 + xx) * 32 + (cb & 31);
            *(bf16x8*)&xs[idx] = v;
        }
        __syncthreads();
    }
    // guard rows (y = -1 and y = 64)
    if (y == 0 || y == 63) {
        const int row = (y == 0) ? 0 : 65;
        uint32_t* xs32 = (uint32_t*)xs;
        for (int c = 0; c < 16; ++c)
            for (int i = tid; i < 1024; i += 256)
                xs32[(((size_t)c * 16 + b) * 66 + row) * 1024 + i] = 0;
    }
}

// ---------- conv: bf16 implicit GEMM, dbuf + counted vmcnt + addr-precompute + setprio
// 1024 blocks, XCD remap; 512 thr / 8 waves; wave w: 64co x 1y x 64x; acc 4x4
// round-5 compute schedule (per-tap A-reads, compiler-pipelined); NO full A-hoist, NO VGPR cap
#define XB 42240   // 10 rowblk * 66 * 64 B
#define WB 36864   // 9 * 64 * 64 B

__global__ __launch_bounds__(512, 1) void k_conv(
    const __bf16* __restrict__ xs, const __bf16* __restrict__ wb,
    const float* __restrict__ demod, float* __restrict__ out)
{
    __shared__ __align__(128) char smem[2 * XB + 2 * WB];

    const int tid  = threadIdx.x;
    const int lane = tid & 63;
    const int wave = tid >> 6;

    const int bid  = blockIdx.x;
    const int r8   = bid & 7;            // XCD
    const int q    = bid >> 3;
    const int co0  = (q & 7) * 64;
    const int pair = (q >> 3) | (r8 << 4);
    const int y0   = (pair & 7) * 8;
    const int b    = pair >> 3;

    const int m  = lane & 15;
    const int g  = lane >> 4;
    const int qA = g ^ ((m >> 1) & 3);

    // zero x-halo rows (xr=0,65) of all 10 rowblocks in BOTH X buffers
    for (int i = tid; i < 640; i += 512) {
        int dw = i & 15, h = i >> 4;
        int buf = h / 20, hh = h % 20;
        int rr = hh >> 1, side = hh & 1;
        ((uint32_t*)smem)[buf * (XB / 4) + (rr * 66 + side * 65) * 16 + dw] = 0;
    }
    asm volatile("s_waitcnt lgkmcnt(0)" ::: "memory");

    // ---- precomputed staging offsets (per thread, chunk-invariant)
    uint32_t soff[10];                 // global element offsets
    uint32_t sdst[10];                 // LDS byte offsets
    const __bf16* sb;
    size_t sstride;
    uint32_t selstride;
    if (wave < 4) {
        sb = xs + (size_t)b * (66 * 64 * 32);
        sstride = (size_t)16 * 66 * 64 * 32;
        selstride = XB;
        #pragma unroll
        for (int i = 0; i < 10; ++i) {
            int o = wave * 10 + i, r = o >> 2, seg = o & 3;
            int p = seg * 64 + lane;
            int xr = 1 + (p >> 2), qd = p & 3;
            int rowg = r * 66 + xr;
            int sq = qd ^ ((rowg >> 1) & 3);
            soff[i] = (uint32_t)(((y0 + r) * 64 + (xr - 1)) * 32 + sq * 8);
            sdst[i] = (uint32_t)((r * 66 + 1) * 64 + seg * 1024);
        }
    } else {
        sb = wb;
        sstride = (size_t)9 * CO_ * 32;
        selstride = WB;
        #pragma unroll
        for (int i = 0; i < 9; ++i) {
            int j = (wave - 4) * 9 + i;
            int p = j * 64 + lane;
            int row = p >> 2, qd = p & 3;
            int sq = qd ^ ((row >> 1) & 3);
            soff[i] = (uint32_t)(((row >> 6) * CO_ + co0 + (row & 63)) * 32 + sq * 8);
            sdst[i] = (uint32_t)(2 * XB + j * 1024);
        }
        soff[9] = 0; sdst[9] = 2 * XB;   // unused
    }

    // ---- precomputed B-read byte bases (per kh,kw; nt adds 1024; nt doesn't affect quad swizzle)
    uint32_t bbase[9];
    #pragma unroll
    for (int kh = 0; kh < 3; ++kh)
        #pragma unroll
        for (int kw = 0; kw < 3; ++kw) {
            int R = (wave + kh) * 66 + m + kw;
            int qB = g ^ ((R >> 1) & 3);
            bbase[kh * 3 + kw] = (uint32_t)(R * 64 + qB * 16);
        }
    const uint32_t abase = (uint32_t)(m * 64 + qA * 16);

    f32x4 acc[4][4];
    #pragma unroll
    for (int mi = 0; mi < 4; ++mi)
        #pragma unroll
        for (int nt = 0; nt < 4; ++nt) acc[mi][nt] = (f32x4){0.f, 0.f, 0.f, 0.f};

    auto stage = [&](const __bf16* base, int sel) {
        uint32_t so = sel * selstride;
        if (wave < 4) {
            #pragma unroll
            for (int i = 0; i < 10; ++i) gload16(base + soff[i], smem + so + sdst[i]);
        } else {
            #pragma unroll
            for (int i = 0; i < 9; ++i) gload16(base + soff[i], smem + so + sdst[i]);
        }
    };

    stage(sb, 0);

    for (int t = 0; t < 16; ++t) {
        if (t < 15) {
            sb += sstride;
            stage(sb, (t + 1) & 1);
            if (wave < 4) asm volatile("s_waitcnt vmcnt(10)" ::: "memory");
            else          asm volatile("s_waitcnt vmcnt(9)"  ::: "memory");
        } else {
            asm volatile("s_waitcnt vmcnt(0)" ::: "memory");
        }
        __builtin_amdgcn_s_barrier();

        const char* xbuf = smem + (t & 1) * XB;
        const char* wbuf = smem + 2 * XB + (t & 1) * WB + abase;

        __builtin_amdgcn_s_setprio(1);
        #pragma unroll
        for (int tp = 0; tp < 9; ++tp) {
            bf16x8 a0 = *(const bf16x8*)(wbuf + tp * 4096);
            bf16x8 a1 = *(const bf16x8*)(wbuf + tp * 4096 + 1024);
            bf16x8 a2 = *(const bf16x8*)(wbuf + tp * 4096 + 2048);
            bf16x8 a3 = *(const bf16x8*)(wbuf + tp * 4096 + 3072);
            #pragma unroll
            for (int nt = 0; nt < 4; ++nt) {
                bf16x8 bv = *(const bf16x8*)(xbuf + bbase[tp] + nt * 1024);
                acc[0][nt] = __builtin_amdgcn_mfma_f32_16x16x32_bf16(a0, bv, acc[0][nt], 0, 0, 0);
                acc[1][nt] = __builtin_amdgcn_mfma_f32_16x16x32_bf16(a1, bv, acc[1][nt], 0, 0, 0);
                acc[2][nt] = __builtin_amdgcn_mfma_f32_16x16x32_bf16(a2, bv, acc[2][nt], 0, 0, 0);
                acc[3][nt] = __builtin_amdgcn_mfma_f32_16x16x32_bf16(a3, bv, acc[3][nt], 0, 0, 0);
            }
        }
        __builtin_amdgcn_s_setprio(0);
        __builtin_amdgcn_s_barrier();
    }

    // ---- epilogue: out[b][co][y][x] = acc * demod[b][co]
    const int y = y0 + wave;
    #pragma unroll
    for (int mi = 0; mi < 4; ++mi) {
        #pragma unroll
        for (int j = 0; j < 4; ++j) {
            const int co = co0 + mi * 16 + g * 4 + j;
            const float dm = demod[b * CO_ + co];
            float* op = out + ((size_t)(b * CO_ + co) * HH + y) * WW;
            #pragma unroll
            for (int nt = 0; nt < 4; ++nt)
                op[nt * 16 + m] = acc[mi][nt][j] * dm;
        }
    }
}

extern "C" void kernel_launch(void* const* d_in, const int* in_sizes, int n_in,
                              void* d_out, int out_size, void* d_ws, size_t ws_size,
                              hipStream_t stream) {
    const float* x      = (const float*)d_in[0];
    const float* style  = (const float*)d_in[1];
    const float* weight = (const float*)d_in[2];
    const float* mod_w  = (const float*)d_in[3];
    const float* mod_b  = (const float*)d_in[4];
    float* out = (float*)d_out;

    char* wsb = (char*)d_ws;
    float*  s_buf = (float*)(wsb + WS_S);
    float*  demod = (float*)(wsb + WS_DEMOD);
    float*  wsq   = (float*)(wsb + WS_WSQ);
    __bf16* wb    = (__bf16*)(wsb + WS_WB);
    __bf16* xs    = (__bf16*)(wsb + WS_XS);

    k_style<<<dim3(B_), dim3(CI_), 0, stream>>>(style, mod_w, mod_b, s_buf);
    k_wprep<<<dim3(CO_ * CI_ / 256), dim3(256), 0, stream>>>(weight, wsq, wb);
    k_demod<<<dim3(B_), dim3(CO_), 0, stream>>>(s_buf, wsq, demod);
    k_xs<<<dim3(HH, B_), dim3(256), 0, stream>>>(x, s_buf, xs);
    k_conv<<<dim3(1024), dim3(512), 0, stream>>>(xs, wb, demod, out);
}